// Round 15
// baseline (1528.980 us; speedup 1.0000x reference)
//
#include <hip/hip_runtime.h>

// CorrelationCost (tfa): out[b, dy*9+dx, y, x] =
//   (1/128) * sum_c prv[b,c,y,x] * nxt[b,c,y+dy-4,x+dx-4], zero-padded.
// B=4, C=128, H=128, W=256 -> out [4, 81, 128, 256] fp32.
//
// R14 -> R15: occupancy still the gap (26.8%). Block = (b, y, dy-triplet);
// 4 waves = 4 channel-QUARTERS (16 pairs each). Grid 1536 = exactly
// 6 blocks/CU x 4 waves = 24 waves/CU co-resident, zero tail. Traffic
// unchanged (786 MB). Main loop = R14's verified CFENCE pipeline,
// 2x-unrolled with A/B register role swap (no copies). Epilogue: 4-way
// tree reduction per dy-chunk, RSTR=36 (b128 at its 8-cycle floor).

#define SR 4
#define ND 9
#define BB 4
#define CC 128
#define HH 128
#define WW 256
#define HW (HH * WW)
#define PADW 264      // 4 left pad + 256 px + 4 right pad (u32 = h2 pair)
#define RSTR 36       // reduction lane stride (u32)

typedef __fp16 h2 __attribute__((ext_vector_type(2)));

static __device__ __forceinline__ h2 pk(float lo, float hi) {
    return __builtin_amdgcn_cvt_pkrtz(lo, hi);   // v_cvt_pkrtz_f16_f32
}
static __device__ __forceinline__ h2 as_h2(unsigned u) {
    union { unsigned u; h2 h; } v; v.u = u; return v.h;
}
static __device__ __forceinline__ unsigned as_u32(h2 h) {
    union { unsigned u; h2 h; } v; v.h = h; return v.u;
}

#define CFENCE asm volatile("" ::: "memory")

__global__ __launch_bounds__(256, 6) void costvol_kernel(
    const float* __restrict__ prv,
    const float* __restrict__ nxt,
    float* __restrict__ out)
{
    // staging: [4 waves][2 bufs][3 rows][PADW] = 6336 u32 = 25344 B
    // reduction union: 2 regions x 64 lanes x RSTR = 4608 u32 (staging dead)
    __shared__ unsigned shraw[4 * 2 * 3 * PADW];

    // XCD-chunked bijective swizzle (1536 % 8 == 0).
    const int nwg  = gridDim.x;
    const int cpx  = nwg >> 3;                 // 192
    const int orig = blockIdx.x;
    const int wid  = (orig & 7) * cpx + (orig >> 3);

    // g fastest: the 3 dy-groups sharing (b, y) are L2-local.
    const int g  = wid % 3;
    const int r_ = wid / 3;
    const int y  = r_ & 127;
    const int b  = r_ >> 7;

    const int tid  = threadIdx.x;
    const int w    = tid >> 6;                 // wave 0..3 = channel quarter
    const int lane = tid & 63;
    const int x0   = lane << 2;                // 4 px per lane
    const int r0   = y + 3 * g - SR;           // first of 3 nxt rows

    bool vok[3];
    #pragma unroll
    for (int j = 0; j < 3; ++j)
        vok[j] = ((unsigned)(r0 + j) < (unsigned)HH);

    unsigned* stg = shraw + w * (2 * 3 * PADW);   // wave-private staging

    // Zero the 4-u32 pads: 2 buf x 3 rows x 2 ends = 12 per wave, once.
    if (lane < 12) {
        const int e  = lane >= 6 ? 1 : 0;
        const int q  = lane - 6 * e;
        const int bf = q & 1;
        const int j  = q >> 1;
        *reinterpret_cast<uint4*>(stg + (bf * 3 + j) * PADW + (e ? 260 : 0)) =
            make_uint4(0u, 0u, 0u, 0u);
    }

    const size_t cbase = (size_t)(b * CC + (w << 5)) * HW;
    const float* pg = prv + cbase + (size_t)y * WW + x0;
    const float* ng = nxt + cbase + (ptrdiff_t)r0 * WW + x0;

    float acc[3][ND][4];
    #pragma unroll
    for (int j = 0; j < 3; ++j)
        #pragma unroll
        for (int dx = 0; dx < ND; ++dx)
            #pragma unroll
            for (int px = 0; px < 4; ++px)
                acc[j][dx][px] = 0.f;

    #define LOADP(k, P0, P1, N) do { \
        const float* pp_ = pg + (size_t)(2 * (k)) * HW; \
        P0 = *reinterpret_cast<const float4*>(pp_); \
        P1 = *reinterpret_cast<const float4*>(pp_ + HW); \
        const float* nn_ = ng + (size_t)(2 * (k)) * HW; \
        _Pragma("unroll") \
        for (int j_ = 0; j_ < 3; ++j_) { \
            if (vok[j_]) { \
                N[j_][0] = *reinterpret_cast<const float4*>(nn_ + j_ * WW); \
                N[j_][1] = *reinterpret_cast<const float4*>(nn_ + j_ * WW + HW); \
            } else { \
                N[j_][0] = make_float4(0.f, 0.f, 0.f, 0.f); \
                N[j_][1] = make_float4(0.f, 0.f, 0.f, 0.f); \
            } \
        } } while (0)

    #define PKN(NH, N) do { \
        _Pragma("unroll") \
        for (int j_ = 0; j_ < 3; ++j_) { \
            NH[j_][0] = as_u32(pk(N[j_][0].x, N[j_][1].x)); \
            NH[j_][1] = as_u32(pk(N[j_][0].y, N[j_][1].y)); \
            NH[j_][2] = as_u32(pk(N[j_][0].z, N[j_][1].z)); \
            NH[j_][3] = as_u32(pk(N[j_][0].w, N[j_][1].w)); \
        } } while (0)

    #define STAGE(bf, NH) do { \
        _Pragma("unroll") \
        for (int j_ = 0; j_ < 3; ++j_) \
            *reinterpret_cast<uint4*>(stg + ((bf) * 3 + j_) * PADW + 4 + x0) = \
                make_uint4(NH[j_][0], NH[j_][1], NH[j_][2], NH[j_][3]); \
        } while (0)

    #define DOTS(bf, NH, P0, P1) do { \
        h2 ph_[4]; \
        ph_[0] = pk(P0.x, P1.x); ph_[1] = pk(P0.y, P1.y); \
        ph_[2] = pk(P0.z, P1.z); ph_[3] = pk(P0.w, P1.w); \
        _Pragma("unroll") \
        for (int j_ = 0; j_ < 3; ++j_) { \
            const unsigned* row_ = stg + ((bf) * 3 + j_) * PADW; \
            const uint4 wl_ = *reinterpret_cast<const uint4*>(row_ + x0); \
            const uint4 wr_ = *reinterpret_cast<const uint4*>(row_ + x0 + 8); \
            h2 n12_[12]; \
            n12_[0] = as_h2(wl_.x); n12_[1] = as_h2(wl_.y); \
            n12_[2] = as_h2(wl_.z); n12_[3] = as_h2(wl_.w); \
            n12_[4] = as_h2(NH[j_][0]); n12_[5] = as_h2(NH[j_][1]); \
            n12_[6] = as_h2(NH[j_][2]); n12_[7] = as_h2(NH[j_][3]); \
            n12_[8] = as_h2(wr_.x); n12_[9] = as_h2(wr_.y); \
            n12_[10] = as_h2(wr_.z); n12_[11] = as_h2(wr_.w); \
            _Pragma("unroll") \
            for (int dx_ = 0; dx_ < ND; ++dx_) \
                _Pragma("unroll") \
                for (int px_ = 0; px_ < 4; ++px_) \
                    acc[j_][dx_][px_] = __builtin_amdgcn_fdot2( \
                        ph_[px_], n12_[dx_ + px_], acc[j_][dx_][px_], false); \
        } } while (0)

    float4 PA0, PA1, PB0, PB1, NA[3][2], NB[3][2];
    unsigned nhA[3][4], nhB[3][4];

    // Prologue: pair 0 loaded, packed, staged to buf0.
    LOADP(0, PA0, PA1, NA);
    PKN(nhA, NA);
    STAGE(0, nhA);
    CFENCE;

    // 16 pairs, 2 phases per iteration; A/B register role swap (no copies).
    for (int k = 0; k < 16; k += 2) {
        // even phase: consume buf0/nhA/PA; load k+1 -> B; stage buf1
        LOADP(k + 1, PB0, PB1, NB);
        DOTS(0, nhA, PA0, PA1);
        PKN(nhB, NB);                      // vmcnt wait lands post-dots
        STAGE(1, nhB);
        CFENCE;
        // odd phase: consume buf1/nhB/PB; load k+2 -> A; stage buf0
        if (k < 14) {
            LOADP(k + 2, PA0, PA1, NA);
            DOTS(1, nhB, PB0, PB1);
            PKN(nhA, NA);
            STAGE(0, nhA);
            CFENCE;
        } else {
            DOTS(1, nhB, PB0, PB1);
        }
    }
    #undef DOTS
    #undef STAGE
    #undef PKN
    #undef LOADP

    // ---- 4-way c-quarter tree reduction + output, 3 dy-chunks ----
    const float invc = 1.0f / (float)CC;
    float* red = reinterpret_cast<float*>(shraw);
    #pragma unroll
    for (int j = 0; j < 3; ++j) {
        const int dy = 3 * g + j;
        __syncthreads();                    // staging (or prior chunk) done
        if (w & 1) {                        // ch 1, 3 write
            float* rp = red + (((w >> 1) << 6) + lane) * RSTR;
            #pragma unroll
            for (int dx = 0; dx < ND; ++dx)
                *reinterpret_cast<float4*>(rp + (dx << 2)) =
                    make_float4(acc[j][dx][0], acc[j][dx][1],
                                acc[j][dx][2], acc[j][dx][3]);
        }
        __syncthreads();
        if (!(w & 1)) {                     // ch 0, 2 accumulate
            const float* rp = red + (((w >> 1) << 6) + lane) * RSTR;
            #pragma unroll
            for (int dx = 0; dx < ND; ++dx) {
                const float4 t = *reinterpret_cast<const float4*>(rp + (dx << 2));
                acc[j][dx][0] += t.x; acc[j][dx][1] += t.y;
                acc[j][dx][2] += t.z; acc[j][dx][3] += t.w;
            }
        }
        __syncthreads();
        if (w == 2) {                       // ch 2 writes its partial
            float* rp = red + lane * RSTR;
            #pragma unroll
            for (int dx = 0; dx < ND; ++dx)
                *reinterpret_cast<float4*>(rp + (dx << 2)) =
                    make_float4(acc[j][dx][0], acc[j][dx][1],
                                acc[j][dx][2], acc[j][dx][3]);
        }
        __syncthreads();
        if (w == 0) {                       // ch 0 finishes + stores
            const float* rp = red + lane * RSTR;
            #pragma unroll
            for (int dx = 0; dx < ND; ++dx) {
                const float4 t = *reinterpret_cast<const float4*>(rp + (dx << 2));
                float* op = out + ((size_t)(b * 81 + dy * ND + dx) * HH + y) * WW + x0;
                *reinterpret_cast<float4*>(op) = make_float4(
                    (acc[j][dx][0] + t.x) * invc, (acc[j][dx][1] + t.y) * invc,
                    (acc[j][dx][2] + t.z) * invc, (acc[j][dx][3] + t.w) * invc);
            }
        }
    }
}

extern "C" void kernel_launch(void* const* d_in, const int* in_sizes, int n_in,
                              void* d_out, int out_size, void* d_ws, size_t ws_size,
                              hipStream_t stream) {
    const float* prv = (const float*)d_in[0];
    const float* nxt = (const float*)d_in[1];
    float* out = (float*)d_out;

    const int nblocks = BB * HH * 3;   // 4 * 128 * 3 = 1536
    costvol_kernel<<<nblocks, 256, 0, stream>>>(prv, nxt, out);
}

// Round 16
// 393.333 us; speedup vs baseline: 3.8872x; 3.8872x over previous
//
#include <hip/hip_runtime.h>

// CorrelationCost (tfa): out[b, dy*9+dx, y, x] =
//   (1/128) * sum_c prv[b,c,y,x] * nxt[b,c,y+dy-4,x+dx-4], zero-padded.
// B=4, C=128, H=128, W=256 -> out [4, 81, 128, 256] fp32.
//
// R15 -> R16: R15's launch_bounds(256,6) capped VGPR at ~85 vs ~170 live
// (acc alone 108) -> accumulator spill to scratch, 6.5 GB HBM, 1529 us.
// Same kernel with the R14-proven bound (256,3): no spill, 12 waves/CU.
// Keeps R15's improvements over R14: A/B register role-swap (no copies),
// 16-pair c-quarter waves, 4-way tree epilogue.

#define SR 4
#define ND 9
#define BB 4
#define CC 128
#define HH 128
#define WW 256
#define HW (HH * WW)
#define PADW 264      // 4 left pad + 256 px + 4 right pad (u32 = h2 pair)
#define RSTR 36       // reduction lane stride (u32)

typedef __fp16 h2 __attribute__((ext_vector_type(2)));

static __device__ __forceinline__ h2 pk(float lo, float hi) {
    return __builtin_amdgcn_cvt_pkrtz(lo, hi);   // v_cvt_pkrtz_f16_f32
}
static __device__ __forceinline__ h2 as_h2(unsigned u) {
    union { unsigned u; h2 h; } v; v.u = u; return v.h;
}
static __device__ __forceinline__ unsigned as_u32(h2 h) {
    union { unsigned u; h2 h; } v; v.h = h; return v.u;
}

#define CFENCE asm volatile("" ::: "memory")

__global__ __launch_bounds__(256, 3) void costvol_kernel(
    const float* __restrict__ prv,
    const float* __restrict__ nxt,
    float* __restrict__ out)
{
    // staging: [4 waves][2 bufs][3 rows][PADW] = 6336 u32 = 25344 B
    // reduction union: 2 regions x 64 lanes x RSTR = 4608 u32 (staging dead)
    __shared__ unsigned shraw[4 * 2 * 3 * PADW];

    // XCD-chunked bijective swizzle (1536 % 8 == 0).
    const int nwg  = gridDim.x;
    const int cpx  = nwg >> 3;                 // 192
    const int orig = blockIdx.x;
    const int wid  = (orig & 7) * cpx + (orig >> 3);

    // g fastest: the 3 dy-groups sharing (b, y) are L2-local.
    const int g  = wid % 3;
    const int r_ = wid / 3;
    const int y  = r_ & 127;
    const int b  = r_ >> 7;

    const int tid  = threadIdx.x;
    const int w    = tid >> 6;                 // wave 0..3 = channel quarter
    const int lane = tid & 63;
    const int x0   = lane << 2;                // 4 px per lane
    const int r0   = y + 3 * g - SR;           // first of 3 nxt rows

    bool vok[3];
    #pragma unroll
    for (int j = 0; j < 3; ++j)
        vok[j] = ((unsigned)(r0 + j) < (unsigned)HH);

    unsigned* stg = shraw + w * (2 * 3 * PADW);   // wave-private staging

    // Zero the 4-u32 pads: 2 buf x 3 rows x 2 ends = 12 per wave, once.
    if (lane < 12) {
        const int e  = lane >= 6 ? 1 : 0;
        const int q  = lane - 6 * e;
        const int bf = q & 1;
        const int j  = q >> 1;
        *reinterpret_cast<uint4*>(stg + (bf * 3 + j) * PADW + (e ? 260 : 0)) =
            make_uint4(0u, 0u, 0u, 0u);
    }

    const size_t cbase = (size_t)(b * CC + (w << 5)) * HW;
    const float* pg = prv + cbase + (size_t)y * WW + x0;
    const float* ng = nxt + cbase + (ptrdiff_t)r0 * WW + x0;

    float acc[3][ND][4];
    #pragma unroll
    for (int j = 0; j < 3; ++j)
        #pragma unroll
        for (int dx = 0; dx < ND; ++dx)
            #pragma unroll
            for (int px = 0; px < 4; ++px)
                acc[j][dx][px] = 0.f;

    #define LOADP(k, P0, P1, N) do { \
        const float* pp_ = pg + (size_t)(2 * (k)) * HW; \
        P0 = *reinterpret_cast<const float4*>(pp_); \
        P1 = *reinterpret_cast<const float4*>(pp_ + HW); \
        const float* nn_ = ng + (size_t)(2 * (k)) * HW; \
        _Pragma("unroll") \
        for (int j_ = 0; j_ < 3; ++j_) { \
            if (vok[j_]) { \
                N[j_][0] = *reinterpret_cast<const float4*>(nn_ + j_ * WW); \
                N[j_][1] = *reinterpret_cast<const float4*>(nn_ + j_ * WW + HW); \
            } else { \
                N[j_][0] = make_float4(0.f, 0.f, 0.f, 0.f); \
                N[j_][1] = make_float4(0.f, 0.f, 0.f, 0.f); \
            } \
        } } while (0)

    #define PKN(NH, N) do { \
        _Pragma("unroll") \
        for (int j_ = 0; j_ < 3; ++j_) { \
            NH[j_][0] = as_u32(pk(N[j_][0].x, N[j_][1].x)); \
            NH[j_][1] = as_u32(pk(N[j_][0].y, N[j_][1].y)); \
            NH[j_][2] = as_u32(pk(N[j_][0].z, N[j_][1].z)); \
            NH[j_][3] = as_u32(pk(N[j_][0].w, N[j_][1].w)); \
        } } while (0)

    #define STAGE(bf, NH) do { \
        _Pragma("unroll") \
        for (int j_ = 0; j_ < 3; ++j_) \
            *reinterpret_cast<uint4*>(stg + ((bf) * 3 + j_) * PADW + 4 + x0) = \
                make_uint4(NH[j_][0], NH[j_][1], NH[j_][2], NH[j_][3]); \
        } while (0)

    #define DOTS(bf, NH, P0, P1) do { \
        h2 ph_[4]; \
        ph_[0] = pk(P0.x, P1.x); ph_[1] = pk(P0.y, P1.y); \
        ph_[2] = pk(P0.z, P1.z); ph_[3] = pk(P0.w, P1.w); \
        _Pragma("unroll") \
        for (int j_ = 0; j_ < 3; ++j_) { \
            const unsigned* row_ = stg + ((bf) * 3 + j_) * PADW; \
            const uint4 wl_ = *reinterpret_cast<const uint4*>(row_ + x0); \
            const uint4 wr_ = *reinterpret_cast<const uint4*>(row_ + x0 + 8); \
            h2 n12_[12]; \
            n12_[0] = as_h2(wl_.x); n12_[1] = as_h2(wl_.y); \
            n12_[2] = as_h2(wl_.z); n12_[3] = as_h2(wl_.w); \
            n12_[4] = as_h2(NH[j_][0]); n12_[5] = as_h2(NH[j_][1]); \
            n12_[6] = as_h2(NH[j_][2]); n12_[7] = as_h2(NH[j_][3]); \
            n12_[8] = as_h2(wr_.x); n12_[9] = as_h2(wr_.y); \
            n12_[10] = as_h2(wr_.z); n12_[11] = as_h2(wr_.w); \
            _Pragma("unroll") \
            for (int dx_ = 0; dx_ < ND; ++dx_) \
                _Pragma("unroll") \
                for (int px_ = 0; px_ < 4; ++px_) \
                    acc[j_][dx_][px_] = __builtin_amdgcn_fdot2( \
                        ph_[px_], n12_[dx_ + px_], acc[j_][dx_][px_], false); \
        } } while (0)

    float4 PA0, PA1, PB0, PB1, NA[3][2], NB[3][2];
    unsigned nhA[3][4], nhB[3][4];

    // Prologue: pair 0 loaded, packed, staged to buf0.
    LOADP(0, PA0, PA1, NA);
    PKN(nhA, NA);
    STAGE(0, nhA);
    CFENCE;

    // 16 pairs, 2 phases per iteration; A/B register role swap (no copies).
    for (int k = 0; k < 16; k += 2) {
        // even phase: consume buf0/nhA/PA; load k+1 -> B; stage buf1
        LOADP(k + 1, PB0, PB1, NB);
        DOTS(0, nhA, PA0, PA1);
        PKN(nhB, NB);                      // vmcnt wait lands post-dots
        STAGE(1, nhB);
        CFENCE;
        // odd phase: consume buf1/nhB/PB; load k+2 -> A; stage buf0
        if (k < 14) {
            LOADP(k + 2, PA0, PA1, NA);
            DOTS(1, nhB, PB0, PB1);
            PKN(nhA, NA);
            STAGE(0, nhA);
            CFENCE;
        } else {
            DOTS(1, nhB, PB0, PB1);
        }
    }
    #undef DOTS
    #undef STAGE
    #undef PKN
    #undef LOADP

    // ---- 4-way c-quarter tree reduction + output, 3 dy-chunks ----
    const float invc = 1.0f / (float)CC;
    float* red = reinterpret_cast<float*>(shraw);
    #pragma unroll
    for (int j = 0; j < 3; ++j) {
        const int dy = 3 * g + j;
        __syncthreads();                    // staging (or prior chunk) done
        if (w & 1) {                        // ch 1, 3 write
            float* rp = red + (((w >> 1) << 6) + lane) * RSTR;
            #pragma unroll
            for (int dx = 0; dx < ND; ++dx)
                *reinterpret_cast<float4*>(rp + (dx << 2)) =
                    make_float4(acc[j][dx][0], acc[j][dx][1],
                                acc[j][dx][2], acc[j][dx][3]);
        }
        __syncthreads();
        if (!(w & 1)) {                     // ch 0, 2 accumulate
            const float* rp = red + (((w >> 1) << 6) + lane) * RSTR;
            #pragma unroll
            for (int dx = 0; dx < ND; ++dx) {
                const float4 t = *reinterpret_cast<const float4*>(rp + (dx << 2));
                acc[j][dx][0] += t.x; acc[j][dx][1] += t.y;
                acc[j][dx][2] += t.z; acc[j][dx][3] += t.w;
            }
        }
        __syncthreads();
        if (w == 2) {                       // ch 2 writes its partial
            float* rp = red + lane * RSTR;
            #pragma unroll
            for (int dx = 0; dx < ND; ++dx)
                *reinterpret_cast<float4*>(rp + (dx << 2)) =
                    make_float4(acc[j][dx][0], acc[j][dx][1],
                                acc[j][dx][2], acc[j][dx][3]);
        }
        __syncthreads();
        if (w == 0) {                       // ch 0 finishes + stores
            const float* rp = red + lane * RSTR;
            #pragma unroll
            for (int dx = 0; dx < ND; ++dx) {
                const float4 t = *reinterpret_cast<const float4*>(rp + (dx << 2));
                float* op = out + ((size_t)(b * 81 + dy * ND + dx) * HH + y) * WW + x0;
                *reinterpret_cast<float4*>(op) = make_float4(
                    (acc[j][dx][0] + t.x) * invc, (acc[j][dx][1] + t.y) * invc,
                    (acc[j][dx][2] + t.z) * invc, (acc[j][dx][3] + t.w) * invc);
            }
        }
    }
}

extern "C" void kernel_launch(void* const* d_in, const int* in_sizes, int n_in,
                              void* d_out, int out_size, void* d_ws, size_t ws_size,
                              hipStream_t stream) {
    const float* prv = (const float*)d_in[0];
    const float* nxt = (const float*)d_in[1];
    float* out = (float*)d_out;

    const int nblocks = BB * HH * 3;   // 4 * 128 * 3 = 1536
    costvol_kernel<<<nblocks, 256, 0, stream>>>(prv, nxt, out);
}

// Round 17
// 53.235 us; speedup vs baseline: 28.7215x; 7.3886x over previous
//
#include <hip/hip_runtime.h>

// CorrelationCost (tfa): out[b, dy*9+dx, y, x] =
//   (1/128) * sum_c prv[b,c,y,x] * nxt[b,c,y+dy-4,x+dx-4], zero-padded.
// B=4, C=128, H=128, W=256 -> out [4, 81, 128, 256] fp32.
//
// R16 -> R17: R15/R16's spill came from the manually unrolled A/B loop
// (full unroll -> live-set explosion), NOT from the c-quarter split or the
// bound. This round: c-quarter occupancy (1536 blocks x 4 waves = 24
// waves/CU requested) with R14's EXACT rolled loop body (runtime bf,
// register copies -- proven spill-free at 51.1 us) and R16's 4-way tree
// epilogue. 16 pairs per wave.

#define SR 4
#define ND 9
#define BB 4
#define CC 128
#define HH 128
#define WW 256
#define HW (HH * WW)
#define PADW 264      // 4 left pad + 256 px + 4 right pad (u32 = h2 pair)
#define RSTR 36       // reduction lane stride (u32)

typedef __fp16 h2 __attribute__((ext_vector_type(2)));

static __device__ __forceinline__ h2 pk(float lo, float hi) {
    return __builtin_amdgcn_cvt_pkrtz(lo, hi);   // v_cvt_pkrtz_f16_f32
}
static __device__ __forceinline__ h2 as_h2(unsigned u) {
    union { unsigned u; h2 h; } v; v.u = u; return v.h;
}
static __device__ __forceinline__ unsigned as_u32(h2 h) {
    union { unsigned u; h2 h; } v; v.h = h; return v.u;
}

#define CFENCE asm volatile("" ::: "memory")

__global__ __launch_bounds__(256, 3) void costvol_kernel(
    const float* __restrict__ prv,
    const float* __restrict__ nxt,
    float* __restrict__ out)
{
    // staging: [4 waves][2 bufs][3 rows][PADW] = 6336 u32 = 25344 B
    // reduction union: 2 regions x 64 lanes x RSTR = 4608 u32 (staging dead)
    __shared__ unsigned shraw[4 * 2 * 3 * PADW];

    // XCD-chunked bijective swizzle (1536 % 8 == 0).
    const int nwg  = gridDim.x;
    const int cpx  = nwg >> 3;                 // 192
    const int orig = blockIdx.x;
    const int wid  = (orig & 7) * cpx + (orig >> 3);

    // g fastest: the 3 dy-groups sharing (b, y) are L2-local.
    const int g  = wid % 3;
    const int r_ = wid / 3;
    const int y  = r_ & 127;
    const int b  = r_ >> 7;

    const int tid  = threadIdx.x;
    const int w    = tid >> 6;                 // wave 0..3 = channel quarter
    const int lane = tid & 63;
    const int x0   = lane << 2;                // 4 px per lane
    const int r0   = y + 3 * g - SR;           // first of 3 nxt rows

    bool vok[3];
    #pragma unroll
    for (int j = 0; j < 3; ++j)
        vok[j] = ((unsigned)(r0 + j) < (unsigned)HH);

    unsigned* stg = shraw + w * (2 * 3 * PADW);   // wave-private staging

    // Zero the 4-u32 pads: 2 buf x 3 rows x 2 ends = 12 per wave, once.
    if (lane < 12) {
        const int e  = lane >= 6 ? 1 : 0;
        const int q  = lane - 6 * e;
        const int bf = q & 1;
        const int j  = q >> 1;
        *reinterpret_cast<uint4*>(stg + (bf * 3 + j) * PADW + (e ? 260 : 0)) =
            make_uint4(0u, 0u, 0u, 0u);
    }

    const size_t cbase = (size_t)(b * CC + (w << 5)) * HW;
    const float* pg = prv + cbase + (size_t)y * WW + x0;
    const float* ng = nxt + cbase + (ptrdiff_t)r0 * WW + x0;

    float acc[3][ND][4];
    #pragma unroll
    for (int j = 0; j < 3; ++j)
        #pragma unroll
        for (int dx = 0; dx < ND; ++dx)
            #pragma unroll
            for (int px = 0; px < 4; ++px)
                acc[j][dx][px] = 0.f;

    #define LOADP(k, P0, P1, N) do { \
        const float* pp_ = pg + (size_t)(2 * (k)) * HW; \
        P0 = *reinterpret_cast<const float4*>(pp_); \
        P1 = *reinterpret_cast<const float4*>(pp_ + HW); \
        const float* nn_ = ng + (size_t)(2 * (k)) * HW; \
        _Pragma("unroll") \
        for (int j_ = 0; j_ < 3; ++j_) { \
            if (vok[j_]) { \
                N[j_][0] = *reinterpret_cast<const float4*>(nn_ + j_ * WW); \
                N[j_][1] = *reinterpret_cast<const float4*>(nn_ + j_ * WW + HW); \
            } else { \
                N[j_][0] = make_float4(0.f, 0.f, 0.f, 0.f); \
                N[j_][1] = make_float4(0.f, 0.f, 0.f, 0.f); \
            } \
        } } while (0)

    #define PKN(NH, N) do { \
        _Pragma("unroll") \
        for (int j_ = 0; j_ < 3; ++j_) { \
            NH[j_][0] = as_u32(pk(N[j_][0].x, N[j_][1].x)); \
            NH[j_][1] = as_u32(pk(N[j_][0].y, N[j_][1].y)); \
            NH[j_][2] = as_u32(pk(N[j_][0].z, N[j_][1].z)); \
            NH[j_][3] = as_u32(pk(N[j_][0].w, N[j_][1].w)); \
        } } while (0)

    #define STAGE(bf, NH) do { \
        _Pragma("unroll") \
        for (int j_ = 0; j_ < 3; ++j_) \
            *reinterpret_cast<uint4*>(stg + ((bf) * 3 + j_) * PADW + 4 + x0) = \
                make_uint4(NH[j_][0], NH[j_][1], NH[j_][2], NH[j_][3]); \
        } while (0)

    float4 P0c, P1c, P0n, P1n, Nc[3][2], Nn[3][2];
    unsigned nhc[3][4], nhn[3][4];

    // Prologue: pair 0 loaded, packed, staged to buf0.
    LOADP(0, P0c, P1c, Nc);
    PKN(nhc, Nc);
    STAGE(0, nhc);
    CFENCE;

    // R14's rolled pipeline, 16 pairs (this wave's channel quarter).
    for (int k = 0; k < 16; ++k) {
        const int bf = k & 1;
        if (k < 15) LOADP(k + 1, P0n, P1n, Nn);   // in flight during dots

        h2 ph[4];
        ph[0] = pk(P0c.x, P1c.x); ph[1] = pk(P0c.y, P1c.y);
        ph[2] = pk(P0c.z, P1c.z); ph[3] = pk(P0c.w, P1c.w);

        #pragma unroll
        for (int j = 0; j < 3; ++j) {
            const unsigned* row = stg + (bf * 3 + j) * PADW;
            const uint4 wl = *reinterpret_cast<const uint4*>(row + x0);
            const uint4 wr = *reinterpret_cast<const uint4*>(row + x0 + 8);
            h2 n12[12];
            n12[0] = as_h2(wl.x); n12[1] = as_h2(wl.y);
            n12[2] = as_h2(wl.z); n12[3] = as_h2(wl.w);
            n12[4] = as_h2(nhc[j][0]); n12[5] = as_h2(nhc[j][1]);
            n12[6] = as_h2(nhc[j][2]); n12[7] = as_h2(nhc[j][3]);
            n12[8] = as_h2(wr.x); n12[9] = as_h2(wr.y);
            n12[10] = as_h2(wr.z); n12[11] = as_h2(wr.w);
            #pragma unroll
            for (int dx = 0; dx < ND; ++dx)
                #pragma unroll
                for (int px = 0; px < 4; ++px)
                    acc[j][dx][px] =
                        __builtin_amdgcn_fdot2(ph[px], n12[dx + px], acc[j][dx][px], false);
        }

        if (k < 15) {
            PKN(nhn, Nn);                    // vmcnt wait lands here, post-dots
            STAGE(bf ^ 1, nhn);
            CFENCE;                          // next iter's reads stay below
            P0c = P0n; P1c = P1n;
            #pragma unroll
            for (int j = 0; j < 3; ++j)
                #pragma unroll
                for (int i = 0; i < 4; ++i)
                    nhc[j][i] = nhn[j][i];
        }
    }
    #undef STAGE
    #undef PKN
    #undef LOADP

    // ---- 4-way c-quarter tree reduction + output, 3 dy-chunks ----
    const float invc = 1.0f / (float)CC;
    float* red = reinterpret_cast<float*>(shraw);
    #pragma unroll
    for (int j = 0; j < 3; ++j) {
        const int dy = 3 * g + j;
        __syncthreads();                    // staging (or prior chunk) done
        if (w & 1) {                        // ch 1, 3 write
            float* rp = red + (((w >> 1) << 6) + lane) * RSTR;
            #pragma unroll
            for (int dx = 0; dx < ND; ++dx)
                *reinterpret_cast<float4*>(rp + (dx << 2)) =
                    make_float4(acc[j][dx][0], acc[j][dx][1],
                                acc[j][dx][2], acc[j][dx][3]);
        }
        __syncthreads();
        if (!(w & 1)) {                     // ch 0, 2 accumulate
            const float* rp = red + (((w >> 1) << 6) + lane) * RSTR;
            #pragma unroll
            for (int dx = 0; dx < ND; ++dx) {
                const float4 t = *reinterpret_cast<const float4*>(rp + (dx << 2));
                acc[j][dx][0] += t.x; acc[j][dx][1] += t.y;
                acc[j][dx][2] += t.z; acc[j][dx][3] += t.w;
            }
        }
        __syncthreads();
        if (w == 2) {                       // ch 2 writes its partial
            float* rp = red + lane * RSTR;
            #pragma unroll
            for (int dx = 0; dx < ND; ++dx)
                *reinterpret_cast<float4*>(rp + (dx << 2)) =
                    make_float4(acc[j][dx][0], acc[j][dx][1],
                                acc[j][dx][2], acc[j][dx][3]);
        }
        __syncthreads();
        if (w == 0) {                       // ch 0 finishes + stores
            const float* rp = red + lane * RSTR;
            #pragma unroll
            for (int dx = 0; dx < ND; ++dx) {
                const float4 t = *reinterpret_cast<const float4*>(rp + (dx << 2));
                float* op = out + ((size_t)(b * 81 + dy * ND + dx) * HH + y) * WW + x0;
                *reinterpret_cast<float4*>(op) = make_float4(
                    (acc[j][dx][0] + t.x) * invc, (acc[j][dx][1] + t.y) * invc,
                    (acc[j][dx][2] + t.z) * invc, (acc[j][dx][3] + t.w) * invc);
            }
        }
    }
}

extern "C" void kernel_launch(void* const* d_in, const int* in_sizes, int n_in,
                              void* d_out, int out_size, void* d_ws, size_t ws_size,
                              hipStream_t stream) {
    const float* prv = (const float*)d_in[0];
    const float* nxt = (const float*)d_in[1];
    float* out = (float*)d_out;

    const int nblocks = BB * HH * 3;   // 4 * 128 * 3 = 1536
    costvol_kernel<<<nblocks, 256, 0, stream>>>(prv, nxt, out);
}

// Round 18
// 50.576 us; speedup vs baseline: 30.2314x; 1.0526x over previous
//
#include <hip/hip_runtime.h>

// CorrelationCost (tfa): out[b, dy*9+dx, y, x] =
//   (1/128) * sum_c prv[b,c,y,x] * nxt[b,c,y+dy-4,x+dx-4], zero-padded.
// B=4, C=128, H=128, W=256 -> out [4, 81, 128, 256] fp32.
//
// FINAL (= R14, best verified at 51.1 us): dy-triplet + c-half hybrid.
// Block = (b, y-pair, dy-triplet g); 4 waves = 2 rows x 2 channel-halves
// (32 pairs each); 768 blocks x 4 waves = 12 waves/CU co-resident.
// 3x traffic cut vs dy-per-block (786 MB L1/L2). Rolled CFENCE pipeline
// (wave-private staging, no barriers in main loop) -- R15/R16 showed any
// multi-phase unroll of the ~110-reg accumulator body spills; rolled +
// register copies is the stable optimum. Epilogue: c-half LDS reduction
// in 3 dy-chunks. Plateau: VALU 36% / L1+L2 ~55% / HBM 18% -- latency-
// bound across pipes; 9 schedule/occupancy variants tested, none beat this.

#define SR 4
#define ND 9
#define BB 4
#define CC 128
#define HH 128
#define WW 256
#define HW (HH * WW)
#define PADW 264      // 4 left pad + 256 px + 4 right pad (u32 = h2 pair)
#define RSTR 40       // reduction lane stride (u32)

typedef __fp16 h2 __attribute__((ext_vector_type(2)));

static __device__ __forceinline__ h2 pk(float lo, float hi) {
    return __builtin_amdgcn_cvt_pkrtz(lo, hi);   // v_cvt_pkrtz_f16_f32
}
static __device__ __forceinline__ h2 as_h2(unsigned u) {
    union { unsigned u; h2 h; } v; v.u = u; return v.h;
}
static __device__ __forceinline__ unsigned as_u32(h2 h) {
    union { unsigned u; h2 h; } v; v.h = h; return v.u;
}

#define CFENCE asm volatile("" ::: "memory")

__global__ __launch_bounds__(256, 3) void costvol_kernel(
    const float* __restrict__ prv,
    const float* __restrict__ nxt,
    float* __restrict__ out)
{
    // staging: [4 waves][2 bufs][3 rows][PADW] = 6336 u32 = 25344 B
    // reduction union: 2 regions x 64 lanes x RSTR = 5120 u32 (staging dead)
    __shared__ unsigned shraw[4 * 2 * 3 * PADW];

    // XCD-chunked bijective swizzle (768 % 8 == 0).
    const int nwg  = gridDim.x;
    const int cpx  = nwg >> 3;                 // 96
    const int orig = blockIdx.x;
    const int wid  = (orig & 7) * cpx + (orig >> 3);

    // g fastest: the 3 dy-groups sharing (b, y-pair) are L2-local.
    const int g  = wid % 3;
    const int r_ = wid / 3;
    const int yp = r_ & 63;
    const int b  = r_ >> 6;

    const int tid  = threadIdx.x;
    const int w    = tid >> 6;                 // wave 0..3
    const int lane = tid & 63;
    const int ry   = w & 1;                    // y row in pair
    const int ch   = w >> 1;                   // channel half
    const int x0   = lane << 2;                // 4 px per lane
    const int y    = (yp << 1) + ry;
    const int r0   = y + 3 * g - SR;           // first of 3 nxt rows

    bool vok[3];
    #pragma unroll
    for (int j = 0; j < 3; ++j)
        vok[j] = ((unsigned)(r0 + j) < (unsigned)HH);

    unsigned* stg = shraw + w * (2 * 3 * PADW);   // wave-private staging

    // Zero the 4-u32 pads: 2 buf x 3 rows x 2 ends = 12 per wave, once.
    if (lane < 12) {
        const int e  = lane >= 6 ? 1 : 0;
        const int q  = lane - 6 * e;
        const int bf = q & 1;
        const int j  = q >> 1;
        *reinterpret_cast<uint4*>(stg + (bf * 3 + j) * PADW + (e ? 260 : 0)) =
            make_uint4(0u, 0u, 0u, 0u);
    }

    const size_t cbase = (size_t)(b * CC + (ch << 6)) * HW;
    const float* pg = prv + cbase + (size_t)y * WW + x0;
    const float* ng = nxt + cbase + (ptrdiff_t)r0 * WW + x0;

    float acc[3][ND][4];
    #pragma unroll
    for (int j = 0; j < 3; ++j)
        #pragma unroll
        for (int dx = 0; dx < ND; ++dx)
            #pragma unroll
            for (int px = 0; px < 4; ++px)
                acc[j][dx][px] = 0.f;

    #define LOADP(k, P0, P1, N) do { \
        const float* pp_ = pg + (size_t)(2 * (k)) * HW; \
        P0 = *reinterpret_cast<const float4*>(pp_); \
        P1 = *reinterpret_cast<const float4*>(pp_ + HW); \
        const float* nn_ = ng + (size_t)(2 * (k)) * HW; \
        _Pragma("unroll") \
        for (int j_ = 0; j_ < 3; ++j_) { \
            if (vok[j_]) { \
                N[j_][0] = *reinterpret_cast<const float4*>(nn_ + j_ * WW); \
                N[j_][1] = *reinterpret_cast<const float4*>(nn_ + j_ * WW + HW); \
            } else { \
                N[j_][0] = make_float4(0.f, 0.f, 0.f, 0.f); \
                N[j_][1] = make_float4(0.f, 0.f, 0.f, 0.f); \
            } \
        } } while (0)

    #define PKN(NH, N) do { \
        _Pragma("unroll") \
        for (int j_ = 0; j_ < 3; ++j_) { \
            NH[j_][0] = as_u32(pk(N[j_][0].x, N[j_][1].x)); \
            NH[j_][1] = as_u32(pk(N[j_][0].y, N[j_][1].y)); \
            NH[j_][2] = as_u32(pk(N[j_][0].z, N[j_][1].z)); \
            NH[j_][3] = as_u32(pk(N[j_][0].w, N[j_][1].w)); \
        } } while (0)

    #define STAGE(bf, NH) do { \
        _Pragma("unroll") \
        for (int j_ = 0; j_ < 3; ++j_) \
            *reinterpret_cast<uint4*>(stg + ((bf) * 3 + j_) * PADW + 4 + x0) = \
                make_uint4(NH[j_][0], NH[j_][1], NH[j_][2], NH[j_][3]); \
        } while (0)

    float4 P0c, P1c, P0n, P1n, Nc[3][2], Nn[3][2];
    unsigned nhc[3][4], nhn[3][4];

    // Prologue: pair 0 loaded, packed, staged to buf0.
    LOADP(0, P0c, P1c, Nc);
    PKN(nhc, Nc);
    STAGE(0, nhc);
    CFENCE;

    for (int k = 0; k < 32; ++k) {
        const int bf = k & 1;
        if (k < 31) LOADP(k + 1, P0n, P1n, Nn);   // in flight during dots

        h2 ph[4];
        ph[0] = pk(P0c.x, P1c.x); ph[1] = pk(P0c.y, P1c.y);
        ph[2] = pk(P0c.z, P1c.z); ph[3] = pk(P0c.w, P1c.w);

        #pragma unroll
        for (int j = 0; j < 3; ++j) {
            const unsigned* row = stg + (bf * 3 + j) * PADW;
            const uint4 wl = *reinterpret_cast<const uint4*>(row + x0);
            const uint4 wr = *reinterpret_cast<const uint4*>(row + x0 + 8);
            h2 n12[12];
            n12[0] = as_h2(wl.x); n12[1] = as_h2(wl.y);
            n12[2] = as_h2(wl.z); n12[3] = as_h2(wl.w);
            n12[4] = as_h2(nhc[j][0]); n12[5] = as_h2(nhc[j][1]);
            n12[6] = as_h2(nhc[j][2]); n12[7] = as_h2(nhc[j][3]);
            n12[8] = as_h2(wr.x); n12[9] = as_h2(wr.y);
            n12[10] = as_h2(wr.z); n12[11] = as_h2(wr.w);
            #pragma unroll
            for (int dx = 0; dx < ND; ++dx)
                #pragma unroll
                for (int px = 0; px < 4; ++px)
                    acc[j][dx][px] =
                        __builtin_amdgcn_fdot2(ph[px], n12[dx + px], acc[j][dx][px], false);
        }

        if (k < 31) {
            PKN(nhn, Nn);                    // vmcnt wait lands here, post-dots
            STAGE(bf ^ 1, nhn);
            CFENCE;                          // next iter's reads stay below
            P0c = P0n; P1c = P1n;
            #pragma unroll
            for (int j = 0; j < 3; ++j)
                #pragma unroll
                for (int i = 0; i < 4; ++i)
                    nhc[j][i] = nhn[j][i];
        }
    }
    #undef STAGE
    #undef PKN
    #undef LOADP

    // ---- c-half reduction + output, 3 dy-chunks (staging area reused) ----
    const float invc = 1.0f / (float)CC;
    #pragma unroll
    for (int j = 0; j < 3; ++j) {
        __syncthreads();                    // prior chunk reads / loop LDS done
        if (ch == 1) {
            float* red = reinterpret_cast<float*>(shraw) + ((ry << 6) + lane) * RSTR;
            #pragma unroll
            for (int dx = 0; dx < ND; ++dx)
                *reinterpret_cast<float4*>(red + (dx << 2)) =
                    make_float4(acc[j][dx][0], acc[j][dx][1],
                                acc[j][dx][2], acc[j][dx][3]);
        }
        __syncthreads();
        if (ch == 0) {
            const float* red = reinterpret_cast<const float*>(shraw) + ((ry << 6) + lane) * RSTR;
            const int dy = 3 * g + j;
            #pragma unroll
            for (int dx = 0; dx < ND; ++dx) {
                const float4 t = *reinterpret_cast<const float4*>(red + (dx << 2));
                float* op = out + ((size_t)(b * 81 + dy * ND + dx) * HH + y) * WW + x0;
                *reinterpret_cast<float4*>(op) = make_float4(
                    (acc[j][dx][0] + t.x) * invc, (acc[j][dx][1] + t.y) * invc,
                    (acc[j][dx][2] + t.z) * invc, (acc[j][dx][3] + t.w) * invc);
            }
        }
    }
}

extern "C" void kernel_launch(void* const* d_in, const int* in_sizes, int n_in,
                              void* d_out, int out_size, void* d_ws, size_t ws_size,
                              hipStream_t stream) {
    const float* prv = (const float*)d_in[0];
    const float* nxt = (const float*)d_in[1];
    float* out = (float*)d_out;

    const int nblocks = BB * (HH / 2) * 3;   // 4 * 64 * 3 = 768
    costvol_kernel<<<nblocks, 256, 0, stream>>>(prv, nxt, out);
}